// Round 9
// baseline (11798.038 us; speedup 1.0000x reference)
//
#include <hip/hip_runtime.h>

// Seq2Seq LSTM forecaster: H=256, B=256, S=672, T=96.
// Round 9: embedded-tag dataflow at SYSTEM scope (r8 minus the broken XCD fast path).
//   - Exchange word: u32 = (tag<<16) | bf16. Producer: ONE sc0 sc1 store per lane
//     (store IS the publish). Consumer: batched dwordx4 sc0 sc1 + v_min tag check
//     (load IS the poll). ~2-3 coherence RTs/tick vs r7's 4+ (drain+flag+poll+load).
//   - r8's sc0-only fast path caused stale-visibility spin-timeouts (absmax 1.7e-2,
//     +10s runtime). sc0 sc1 is the op-mix r6/r7 proved correct. Fast path deleted.
//   - Tag/parity protocol re-verified: every slab overwrite is gated (via observed
//     stores + data dependence) behind all readers of the overwritten generation.
//   - Slabs zeroed each launch (tag 0 == empty; replay-safe monotonic >= check).

#define S_LEN 672
#define T_LEN 96
#define HDIM  256
#define SPIN_MAX (1 << 15)
#define DTAG 1024u

typedef short short8 __attribute__((ext_vector_type(8)));
typedef float f32x4  __attribute__((ext_vector_type(4)));
typedef unsigned u32x4 __attribute__((ext_vector_type(4)));
typedef unsigned short u16;
typedef unsigned long long u64;

// ---- workspace layout (bytes) ----
#define OFF_FLAG 0                                   // dtype mode flag
#define OFF_PART 4096                                // u64 [2][16g][16m][16b]
#define OFF_H0   (OFF_PART + 2*16*256*8)             // u32 [16g][2][16b*256ch]
#define OFF_H1   (OFF_H0 + 16*2*4096*4)
#define ZERO_END (OFF_H1 + 16*2*4096*4)              // ~1.1 MB zeroed per launch
#define OFF_F0   ZERO_END                            // u16 [16g][16b][256ch] h0 final
#define OFF_F1   (OFF_F0 + 16*4096*2)                // u16 h1 final
#define OFF_C0   (OFF_F1 + 16*4096*2)                // f32 [256][256]
#define OFF_C1   (OFF_C0 + 256*256*4)

__device__ __forceinline__ unsigned short f2bf(float f) {
  unsigned u = __float_as_uint(f);
  u += 0x7FFFu + ((u >> 16) & 1u);
  return (unsigned short)(u >> 16);
}
__device__ __forceinline__ float bf2f(unsigned short s) {
  return __uint_as_float(((unsigned)s) << 16);
}
__device__ __forceinline__ float ld_scalar(const void* p, long idx, int mode) {
  if (mode) return bf2f(((const u16*)p)[idx]);
  return ((const float*)p)[idx];
}
__device__ __forceinline__ short8 ld_frag8w(const void* p, long row, long ld, long k0, int mode) {
  if (mode) {
    return *(const short8*)((const u16*)p + row * ld + k0);
  } else {
    const float* f = (const float*)p + row * ld + k0;
    short8 r;
#pragma unroll
    for (int i = 0; i < 8; i++) r[i] = (short)f2bf(f[i]);
    return r;
  }
}
__device__ __forceinline__ void st_out(void* out, size_t idx, float v, int mode) {
  if (mode) ((u16*)out)[idx] = f2bf(v);
  else      ((float*)out)[idx] = v;
}
__device__ __forceinline__ float sigm(float x) { return 1.f / (1.f + __expf(-x)); }
__device__ __forceinline__ unsigned umn(unsigned a, unsigned b) { return a < b ? a : b; }

__device__ __forceinline__ f32x4 mfma_bf16(short8 a, short8 b, f32x4 c) {
  return __builtin_amdgcn_mfma_f32_16x16x32_bf16(a, b, c, 0, 0, 0);
}
__device__ __forceinline__ void waitv0() {
  asm volatile("s_waitcnt vmcnt(0)" ::: "memory");
  __builtin_amdgcn_sched_barrier(0);
}

// ---- system-scope data plane (sc0 sc1 = coherence-point access; r7-proven) ----
__device__ __forceinline__ void ld16(const unsigned* b, u32x4* c) {
  asm volatile(
    "global_load_dwordx4 %0, %16, off sc0 sc1\n\t"
    "global_load_dwordx4 %1, %16, off offset:16 sc0 sc1\n\t"
    "global_load_dwordx4 %2, %16, off offset:128 sc0 sc1\n\t"
    "global_load_dwordx4 %3, %16, off offset:144 sc0 sc1\n\t"
    "global_load_dwordx4 %4, %16, off offset:256 sc0 sc1\n\t"
    "global_load_dwordx4 %5, %16, off offset:272 sc0 sc1\n\t"
    "global_load_dwordx4 %6, %16, off offset:384 sc0 sc1\n\t"
    "global_load_dwordx4 %7, %16, off offset:400 sc0 sc1\n\t"
    "global_load_dwordx4 %8, %16, off offset:512 sc0 sc1\n\t"
    "global_load_dwordx4 %9, %16, off offset:528 sc0 sc1\n\t"
    "global_load_dwordx4 %10, %16, off offset:640 sc0 sc1\n\t"
    "global_load_dwordx4 %11, %16, off offset:656 sc0 sc1\n\t"
    "global_load_dwordx4 %12, %16, off offset:768 sc0 sc1\n\t"
    "global_load_dwordx4 %13, %16, off offset:784 sc0 sc1\n\t"
    "global_load_dwordx4 %14, %16, off offset:896 sc0 sc1\n\t"
    "global_load_dwordx4 %15, %16, off offset:912 sc0 sc1"
    : "=&v"(c[0]), "=&v"(c[1]), "=&v"(c[2]), "=&v"(c[3]),
      "=&v"(c[4]), "=&v"(c[5]), "=&v"(c[6]), "=&v"(c[7]),
      "=&v"(c[8]), "=&v"(c[9]), "=&v"(c[10]), "=&v"(c[11]),
      "=&v"(c[12]), "=&v"(c[13]), "=&v"(c[14]), "=&v"(c[15])
    : "v"(b) : "memory");
}
__device__ __forceinline__ void ld4(const unsigned* b, u32x4* c) {
  asm volatile(
    "global_load_dwordx4 %0, %4, off sc0 sc1\n\t"
    "global_load_dwordx4 %1, %4, off offset:16 sc0 sc1\n\t"
    "global_load_dwordx4 %2, %4, off offset:128 sc0 sc1\n\t"
    "global_load_dwordx4 %3, %4, off offset:144 sc0 sc1"
    : "=&v"(c[0]), "=&v"(c[1]), "=&v"(c[2]), "=&v"(c[3]) : "v"(b) : "memory");
}
__device__ __forceinline__ void st32(unsigned* p, unsigned v) {
  asm volatile("global_store_dword %0, %1, off sc0 sc1" :: "v"(p), "v"(v) : "memory");
}
__device__ __forceinline__ u64 ld64(const u64* p) {
  u64 v;
  asm volatile("global_load_dwordx2 %0, %1, off sc0 sc1" : "=&v"(v) : "v"(p) : "memory");
  return v;
}
__device__ __forceinline__ void st64(u64* p, u64 v) {
  asm volatile("global_store_dwordx2 %0, %1, off sc0 sc1" :: "v"(p), "v"(v) : "memory");
}

// ---- tag-check + pack ----
__device__ __forceinline__ unsigned umin16(const u32x4* c) {
  unsigned m = 0xFFFFFFFFu;
#pragma unroll
  for (int i = 0; i < 16; i++) {
    m = umn(m, c[i].x); m = umn(m, c[i].y); m = umn(m, c[i].z); m = umn(m, c[i].w);
  }
  return m;
}
__device__ __forceinline__ unsigned umin4(const u32x4* c) {
  unsigned m = 0xFFFFFFFFu;
#pragma unroll
  for (int i = 0; i < 4; i++) {
    m = umn(m, c[i].x); m = umn(m, c[i].y); m = umn(m, c[i].z); m = umn(m, c[i].w);
  }
  return m;
}
union PU { u32x4 u; short8 s; };
__device__ __forceinline__ short8 pack2(u32x4 a, u32x4 b) {
  u32x4 r;
  r.x = __builtin_amdgcn_perm(a.y, a.x, 0x05040100u);   // (lo16(a.x), lo16(a.y))
  r.y = __builtin_amdgcn_perm(a.w, a.z, 0x05040100u);
  r.z = __builtin_amdgcn_perm(b.y, b.x, 0x05040100u);
  r.w = __builtin_amdgcn_perm(b.w, b.z, 0x05040100u);
  PU p; p.u = r; return p.s;
}
__device__ __forceinline__ void pack16(const u32x4* c, short8* f) {
#pragma unroll
  for (int kf = 0; kf < 8; kf++) f[kf] = pack2(c[2 * kf], c[2 * kf + 1]);
}

// ---- poll primitives (load IS the poll; monotonic >= tag check) ----
__device__ __forceinline__ void poll_one(const unsigned* b, unsigned tg, short8* f) {
  u32x4 c[16];
  const unsigned T = tg << 16;
  int spin = 0;
  for (;;) {
    ld16(b, c);
    waitv0();
    if (__all(umin16(c) >= T)) break;
    if (++spin > SPIN_MAX) break;
  }
  pack16(c, f);
}
__device__ __forceinline__ void poll_two(const unsigned* b0, unsigned tg0, short8* f0,
                                         const unsigned* b1, unsigned tg1, short8* f1) {
  u32x4 c0[16], c1[16];
  const unsigned T0 = tg0 << 16, T1 = tg1 << 16;
  int spin = 0;
  for (;;) {
    ld16(b0, c0);
    ld16(b1, c1);
    waitv0();
    if (__all((umin16(c0) >= T0) && (umin16(c1) >= T1))) break;
    if (++spin > SPIN_MAX) break;
  }
  pack16(c0, f0);
  pack16(c1, f1);
}
__device__ __forceinline__ float poll_ap(const unsigned* b, unsigned tg, short8* f,
                                         const u64* pp, unsigned ptg) {
  u32x4 c[16];
  u64 pv = 0;
  const unsigned T = tg << 16;
  int spin = 0;
  for (;;) {
    ld16(b, c);
    pv = ld64(pp);
    waitv0();
    if (__all((umin16(c) >= T) && ((unsigned)(pv >> 32) >= ptg))) break;
    if (++spin > SPIN_MAX) break;
  }
  pack16(c, f);
  return __uint_as_float((unsigned)pv);
}
__device__ __forceinline__ void poll_head(const unsigned* b, unsigned tg, short8* f) {
  u32x4 c[4];
  const unsigned T = tg << 16;
  int spin = 0;
  for (;;) {
    ld4(b, c);
    waitv0();
    if (__all(umin4(c) >= T)) break;
    if (++spin > SPIN_MAX) break;
  }
  f[0] = pack2(c[0], c[1]);
  f[1] = pack2(c[2], c[3]);
}
__device__ __forceinline__ float poll_part(const u64* pp, unsigned ptg) {
  u64 pv = 0;
  int spin = 0;
  for (;;) {
    pv = ld64(pp);
    waitv0();
    if (__all((unsigned)(pv >> 32) >= ptg)) break;
    if (++spin > SPIN_MAX) break;
  }
  return __uint_as_float((unsigned)pv);
}

// ---- dtype detector ----
__global__ void detect_mode(const unsigned* __restrict__ feat, unsigned* __restrict__ flag) {
  const int t = threadIdx.x;
  int cnt = 0;
#pragma unroll
  for (int i = 0; i < 8; i++) {
    const unsigned wv = feat[t * 8 + i];
    const unsigned e = (wv >> 7) & 0xFFu;
    cnt += (e >= 100u && e <= 130u) ? 1 : 0;
  }
#pragma unroll
  for (int o = 32; o > 0; o >>= 1) cnt += __shfl_down(cnt, o, 64);
  if (t == 0) flag[0] = (cnt >= 256) ? 1u : 0u;
}

// ============================ encoder ============================
// Tick t: layer0 step t (t<672), layer1 step t-1 (t>=1). h0(t): parity t&1 tag t+1.
// h1(t-1) (at tick t): parity t&1 tag t+1. Reads at tick t: h0(t-1) + h1(t-2),
// parity (t+1)&1, tag t. Every overwrite is 2 generations past its readers, gated
// through observed stores + data dependence (store of gen g requires reads of g-1).
__global__ void __launch_bounds__(256, 1)
enc_kernel(const void* __restrict__ feat,
           const void* __restrict__ Wih0, const void* __restrict__ Whh0, const void* __restrict__ b0,
           const void* __restrict__ Wih1, const void* __restrict__ Whh1, const void* __restrict__ b1,
           char* __restrict__ ws) {
  const int mode = (int)*(const unsigned*)(ws + OFF_FLAG);
  const int lane = threadIdx.x & 63;
  const int w    = threadIdx.x >> 6;
  const int bId  = blockIdx.x;
  const int g    = (bId & 7) * 2 + ((bId >> 3) & 1);
  const int m    = bId >> 4;

  const int fcol = lane & 15;                // batch row (fragments AND pointwise)
  const int kq   = lane >> 4;                // k-quarter / channel sub-index
  const int chq  = m * 16 + w * 4 + kq;      // this lane's pointwise channel
  const int bgl  = g * 16 + fcol;            // this lane's batch
  const int lof  = fcol * 256 + kq * 8;

  unsigned* h0s = (unsigned*)(ws + OFF_H0) + (size_t)g * 2 * 4096;
  unsigned* h1s = (unsigned*)(ws + OFF_H1) + (size_t)g * 2 * 4096;
  u16* f0s = (u16*)(ws + OFF_F0) + (size_t)g * 4096;
  u16* f1s = (u16*)(ws + OFF_F1) + (size_t)g * 4096;
  float* c0ws = (float*)(ws + OFF_C0);
  float* c1ws = (float*)(ws + OFF_C1);

  // weight fragments: wave w owns gate-cols n = 16w + fcol; row = (n&3)*H + m*16 + (n>>2)
  const int n    = 16 * w + fcol;
  const int grow = (n & 3) * HDIM + m * 16 + (n >> 2);
  short8 wh0[8], wi1[8], wh1[8];
#pragma unroll
  for (int kf = 0; kf < 8; kf++) {
    const int k0 = kf * 32 + kq * 8;
    wh0[kf] = ld_frag8w(Whh0, grow, HDIM, k0, mode);
    wi1[kf] = ld_frag8w(Wih1, grow, HDIM, k0, mode);
    wh1[kf] = ld_frag8w(Whh1, grow, HDIM, k0, mode);
  }
  float wx[4], bb0[4], bb1[4];
#pragma unroll
  for (int gt = 0; gt < 4; gt++) {
    wx[gt]  = ld_scalar(Wih0, gt * HDIM + chq, mode);
    bb0[gt] = ld_scalar(b0,   gt * HDIM + chq, mode);
    bb1[gt] = ld_scalar(b1,   gt * HDIM + chq, mode);
  }
  float c0 = 0.f, c1 = 0.f, h0keep = 0.f, h1fin = 0.f;

  for (int t = 0; t <= S_LEN; t++) {
    const int pr = (t + 1) & 1, pw = t & 1;
    short8 a0[8], a1[8];
    if (t >= 2)
      poll_two(h0s + pr * 4096 + lof, (unsigned)t, a0,
               h1s + pr * 4096 + lof, (unsigned)t, a1);
    else if (t == 1)
      poll_one(h0s + pr * 4096 + lof, 1u, a0);

    f32x4 acc0 = {0.f, 0.f, 0.f, 0.f}, acc1 = {0.f, 0.f, 0.f, 0.f};
    if (t >= 1 && t < S_LEN) {
#pragma unroll
      for (int kf = 0; kf < 8; kf++) acc0 = mfma_bf16(wh0[kf], a0[kf], acc0);  // swapped
    }
    if (t >= 1) {
#pragma unroll
      for (int kf = 0; kf < 8; kf++) acc1 = mfma_bf16(wi1[kf], a0[kf], acc1);
      if (t >= 2) {
#pragma unroll
        for (int kf = 0; kf < 8; kf++) acc1 = mfma_bf16(wh1[kf], a1[kf], acc1);
      }
    }
    // direct pointwise: acc[i] = gate i of (chq, batch fcol)
    if (t < S_LEN) {
      const float x = ld_scalar(feat, (long)bgl * S_LEN + t, mode);
      const float gi = acc0[0] + x * wx[0] + bb0[0];
      const float gf = acc0[1] + x * wx[1] + bb0[1];
      const float gg = acc0[2] + x * wx[2] + bb0[2];
      const float go = acc0[3] + x * wx[3] + bb0[3];
      c0 = sigm(gf) * c0 + sigm(gi) * tanhf(gg);
      const float h0v = sigm(go) * tanhf(c0);
      h0keep = h0v;
      st32(h0s + pw * 4096 + fcol * 256 + chq, ((unsigned)(t + 1) << 16) | f2bf(h0v));
    }
    if (t >= 1) {
      const float gi = acc1[0] + bb1[0];
      const float gf = acc1[1] + bb1[1];
      const float gg = acc1[2] + bb1[2];
      const float go = acc1[3] + bb1[3];
      c1 = sigm(gf) * c1 + sigm(gi) * tanhf(gg);
      const float h1v = sigm(go) * tanhf(c1);
      if (t < S_LEN)
        st32(h1s + pw * 4096 + fcol * 256 + chq, ((unsigned)(t + 1) << 16) | f2bf(h1v));
      else h1fin = h1v;
    }
  }
  // handoff (plain; kernel boundary provides ordering + L2 writeback)
  f0s[fcol * 256 + chq] = f2bf(h0keep);
  f1s[fcol * 256 + chq] = f2bf(h1fin);
  c0ws[(size_t)bgl * HDIM + chq] = c0;
  c1ws[(size_t)bgl * HDIM + chq] = c1;
}

// ============================ decoder ============================
// dec h0(s)/h1(s): parity s&1, tag DTAG+s (DTAG > all enc tags). partial(s):
// parity s&1, tag s+1 (u64). s=0 state from fin slabs (kernel-boundary ordered).
__global__ void __launch_bounds__(256, 1)
dec_kernel(const void* __restrict__ Wih0, const void* __restrict__ Whh0, const void* __restrict__ b0,
           const void* __restrict__ Wih1, const void* __restrict__ Whh1, const void* __restrict__ b1,
           const void* __restrict__ W1, const void* __restrict__ b1h, const void* __restrict__ W2,
           const void* __restrict__ b2, char* __restrict__ ws, void* __restrict__ out) {
  const int mode = (int)*(const unsigned*)(ws + OFF_FLAG);
  const int tid  = threadIdx.x;
  const int lane = tid & 63;
  const int w    = tid >> 6;
  const int bId  = blockIdx.x;
  const int g    = (bId & 7) * 2 + ((bId >> 3) & 1);
  const int m    = bId >> 4;

  const int fcol = lane & 15;
  const int kq   = lane >> 4;
  const int chq  = m * 16 + w * 4 + kq;
  const int bgl  = g * 16 + fcol;
  const int lof  = fcol * 256 + kq * 8;

  unsigned* h0s = (unsigned*)(ws + OFF_H0) + (size_t)g * 2 * 4096;
  unsigned* h1s = (unsigned*)(ws + OFF_H1) + (size_t)g * 2 * 4096;
  u16* f0s = (u16*)(ws + OFF_F0) + (size_t)g * 4096;
  u16* f1s = (u16*)(ws + OFF_F1) + (size_t)g * 4096;
  u64* partial = (u64*)(ws + OFF_PART);
  float* c0ws = (float*)(ws + OFF_C0);
  float* c1ws = (float*)(ws + OFF_C1);

  __shared__ float part[4 * 256];
  __shared__ float redv[256];
  __shared__ float xacc[256];

  const int n    = 16 * w + fcol;
  const int grow = (n & 3) * HDIM + m * 16 + (n >> 2);
  short8 wh0[8], wi1[8], wh1[8], ww1[2];
#pragma unroll
  for (int kf = 0; kf < 8; kf++) {
    const int k0 = kf * 32 + kq * 8;
    wh0[kf] = ld_frag8w(Whh0, grow, HDIM, k0, mode);
    wi1[kf] = ld_frag8w(Wih1, grow, HDIM, k0, mode);
    wh1[kf] = ld_frag8w(Whh1, grow, HDIM, k0, mode);
  }
#pragma unroll
  for (int kf2 = 0; kf2 < 2; kf2++) {
    const int k0 = w * 64 + kf2 * 32 + kq * 8;       // K-split of head GEMM across waves
    ww1[kf2] = ld_frag8w(W1, m * 16 + fcol, HDIM, k0, mode);
  }
  float wx[4], bb0[4], bb1[4];
#pragma unroll
  for (int gt = 0; gt < 4; gt++) {
    wx[gt]  = ld_scalar(Wih0, gt * HDIM + chq, mode);
    bb0[gt] = ld_scalar(b0,   gt * HDIM + chq, mode);
    bb1[gt] = ld_scalar(b1,   gt * HDIM + chq, mode);
  }
  const int hb = tid & 15, hcl = tid >> 4;           // head reduce roles
  const float b1hv = ld_scalar(b1h, m * 16 + hcl, mode);
  const float w2v  = ld_scalar(W2,  m * 16 + hcl, mode);
  const float b2v  = ld_scalar(b2, 0, mode);

  float c0 = c0ws[(size_t)bgl * HDIM + chq];
  float c1 = c1ws[(size_t)bgl * HDIM + chq];

  for (int s = 0; s < T_LEN; s++) {
    const int ppr = (s - 1) & 1, pcur = s & 1;
    // ---------- phase A: pred(s-1) gather + layer0 ----------
    float x = 0.f;
    short8 a0[8];
    if (s > 0) {
      const u64* pp = partial + (((size_t)ppr * 16 + g) * 16 + (tid >> 4)) * 16 + (tid & 15);
      const float pv = poll_ap(h0s + ppr * 4096 + lof, DTAG + (unsigned)s - 1u, a0,
                               pp, (unsigned)s);
      xacc[(tid & 15) * 16 + (tid >> 4)] = pv;
      __syncthreads();
#pragma unroll
      for (int j = 0; j < 16; j++) x += xacc[fcol * 16 + j];
      if (m == 0 && tid < 16)
        st_out(out, (size_t)(g * 16 + tid) * T_LEN + (s - 1), x, mode);
    } else {
      const u16* fb = f0s + lof;
#pragma unroll
      for (int kf = 0; kf < 8; kf++) a0[kf] = *(const short8*)(fb + kf * 32);
    }
    {
      f32x4 acc = {0.f, 0.f, 0.f, 0.f};
#pragma unroll
      for (int kf = 0; kf < 8; kf++) acc = mfma_bf16(wh0[kf], a0[kf], acc);
      const float gi = acc[0] + x * wx[0] + bb0[0];
      const float gf = acc[1] + x * wx[1] + bb0[1];
      const float gg = acc[2] + x * wx[2] + bb0[2];
      const float go = acc[3] + x * wx[3] + bb0[3];
      c0 = sigm(gf) * c0 + sigm(gi) * tanhf(gg);
      const float h0v = sigm(go) * tanhf(c0);
      st32(h0s + pcur * 4096 + fcol * 256 + chq,
           ((DTAG + (unsigned)s) << 16) | f2bf(h0v));
    }
    // ---------- phase B: layer1 ----------
    {
      short8 ay[8], a1[8];
      if (s > 0) {
        poll_two(h0s + pcur * 4096 + lof, DTAG + (unsigned)s, ay,
                 h1s + ppr * 4096 + lof, DTAG + (unsigned)s - 1u, a1);
      } else {
        poll_one(h0s + pcur * 4096 + lof, DTAG, ay);
        const u16* fb = f1s + lof;
#pragma unroll
        for (int kf = 0; kf < 8; kf++) a1[kf] = *(const short8*)(fb + kf * 32);
      }
      f32x4 acc = {0.f, 0.f, 0.f, 0.f};
#pragma unroll
      for (int kf = 0; kf < 8; kf++) {
        acc = mfma_bf16(wi1[kf], ay[kf], acc);
        acc = mfma_bf16(wh1[kf], a1[kf], acc);
      }
      const float gi = acc[0] + bb1[0];
      const float gf = acc[1] + bb1[1];
      const float gg = acc[2] + bb1[2];
      const float go = acc[3] + bb1[3];
      c1 = sigm(gf) * c1 + sigm(gi) * tanhf(gg);
      const float h1v = sigm(go) * tanhf(c1);
      st32(h1s + pcur * 4096 + fcol * 256 + chq,
           ((DTAG + (unsigned)s) << 16) | f2bf(h1v));
    }
    // ---------- phase C: head (Linear->ReLU->Linear), K-split across waves ----------
    {
      short8 ah[2];
      poll_head(h1s + pcur * 4096 + (fcol * 256 + w * 64 + kq * 8),
                DTAG + (unsigned)s, ah);
      f32x4 acc = {0.f, 0.f, 0.f, 0.f};
      acc = mfma_bf16(ww1[0], ah[0], acc);
      acc = mfma_bf16(ww1[1], ah[1], acc);
      // acc[i] = hidden[hch m*16 + 4kq+i][batch fcol] (K-slice w)
      *(f32x4*)&part[w * 256 + fcol * 16 + kq * 4] = acc;
      __syncthreads();
      float hid = part[0 * 256 + hb * 16 + hcl] + part[1 * 256 + hb * 16 + hcl]
                + part[2 * 256 + hb * 16 + hcl] + part[3 * 256 + hb * 16 + hcl] + b1hv;
      hid = fmaxf(hid, 0.f);
      redv[hcl * 16 + hb] = hid * w2v;
      __syncthreads();
      if (tid < 16) {
        float a = (m == 0) ? b2v : 0.f;
#pragma unroll
        for (int cc = 0; cc < 16; cc++) a += redv[cc * 16 + tid];
        st64(partial + (((size_t)pcur * 16 + g) * 16 + m) * 16 + tid,
             ((u64)(unsigned)(s + 1) << 32) | (u64)__float_as_uint(a));
      }
      __syncthreads();
    }
  }
  // final output column: pred(T-1), partial tag T_LEN at parity 1
  if (m == 0) {
    const u64* pp = partial + (((size_t)1 * 16 + g) * 16 + (tid >> 4)) * 16 + (tid & 15);
    const float pv = poll_part(pp, (unsigned)T_LEN);
    xacc[(tid & 15) * 16 + (tid >> 4)] = pv;
    __syncthreads();
    if (tid < 16) {
      float x = 0.f;
#pragma unroll
      for (int j = 0; j < 16; j++) x += xacc[tid * 16 + j];
      st_out(out, (size_t)(g * 16 + tid) * T_LEN + (T_LEN - 1), x, mode);
    }
  }
}

extern "C" void kernel_launch(void* const* d_in, const int* in_sizes, int n_in,
                              void* d_out, int out_size, void* d_ws, size_t ws_size,
                              hipStream_t stream) {
  char* ws = (char*)d_ws;
  // zero partials + h slabs every launch (tag 0 == empty; replay-safe)
  hipMemsetAsync(ws, 0, ZERO_END, stream);
  detect_mode<<<1, 64, 0, stream>>>((const unsigned*)d_in[0], (unsigned*)(ws + OFF_FLAG));
  enc_kernel<<<256, 256, 0, stream>>>(d_in[0], d_in[1], d_in[2], d_in[3],
                                      d_in[4], d_in[5], d_in[6], ws);
  dec_kernel<<<256, 256, 0, stream>>>(d_in[7], d_in[8], d_in[9], d_in[10], d_in[11], d_in[12],
                                      d_in[13], d_in[14], d_in[15], d_in[16], ws, d_out);
}

// Round 11
// 3199.179 us; speedup vs baseline: 3.6878x; 3.6878x over previous
//
#include <hip/hip_runtime.h>

// Seq2Seq LSTM forecaster: H=256, B=256, S=672, T=96.
// Round 11: EXACT r7 (4.11ms, passed) + ONE change: cooperative LDS staging of the
// h-slabs (4x cut of the 64KB/wg/tick redundant system-scope reads that inflate RTs).
//   - r7 helpers byte-identical: pollge (16 wg-flags @32B, s_sleep), wg_publish
//     (drain -> __syncthreads -> tid0 flag store), per-lane st16 h-stores, layout.
//   - Staging: each thread ld32B's its own 32B slice -> waitv0 -> short8-typed LDS
//     writes -> __syncthreads -> fragment reads sh[fcol][kf*4+kq]. No type punning,
//     no packed stores, no per-wave flags (the three r10 suspects are dropped).
//   - Write-after-read LDS hazard: wg_publish's internal barrier separates tick t's
//     ds_reads from tick t+1's ds_writes (verified chain).
//   - Decoder phase C keeps r7's direct loads (no redundancy there).

#define S_LEN 672
#define T_LEN 96
#define HDIM  256
#define SPIN_MAX (1 << 14)

typedef short short8 __attribute__((ext_vector_type(8)));
typedef float f32x4  __attribute__((ext_vector_type(4)));
typedef unsigned short u16;

// ---- workspace layout (bytes) ---- (r7 verbatim)
#define OFF_FLAG 0                                  // dtype mode flag
#define OFF_FE   1024                               // enc flags: [16g][16wg] u32 @ 32B stride
#define OFF_FD   (OFF_FE + 16*16*32)                // dec flags: same shape
#define OFF_PART (OFF_FD + 16*16*32)                // f32 [2][16g][16m][16b]
#define ZERO_END (OFF_PART + 2*16*256*4)
#define OFF_H0   ZERO_END                           // u16 [16g][2][16b][256ch]
#define OFF_H1   (OFF_H0 + 16*2*4096*2)
#define OFF_F0   (OFF_H1 + 16*2*4096*2)             // u16 [16g][16b][256ch] h0 final
#define OFF_F1   (OFF_F0 + 16*4096*2)               // u16 h1 final
#define OFF_C0   (OFF_F1 + 16*4096*2)               // f32 [256][256]
#define OFF_C1   (OFF_C0 + 256*256*4)

__device__ __forceinline__ unsigned short f2bf(float f) {
  unsigned u = __float_as_uint(f);
  u += 0x7FFFu + ((u >> 16) & 1u);
  return (unsigned short)(u >> 16);
}
__device__ __forceinline__ float bf2f(unsigned short s) {
  return __uint_as_float(((unsigned)s) << 16);
}
__device__ __forceinline__ float ld_scalar(const void* p, long idx, int mode) {
  if (mode) return bf2f(((const u16*)p)[idx]);
  return ((const float*)p)[idx];
}
__device__ __forceinline__ short8 ld_frag8(const void* p, long row, long ld, long k0, int mode) {
  if (mode) {
    return *(const short8*)((const u16*)p + row * ld + k0);
  } else {
    const float* f = (const float*)p + row * ld + k0;
    short8 r;
#pragma unroll
    for (int i = 0; i < 8; i++) r[i] = (short)f2bf(f[i]);
    return r;
  }
}
__device__ __forceinline__ void st_out(void* out, size_t idx, float v, int mode) {
  if (mode) ((u16*)out)[idx] = f2bf(v);
  else      ((float*)out)[idx] = v;
}
__device__ __forceinline__ float sigm(float x) { return 1.f / (1.f + __expf(-x)); }

__device__ __forceinline__ f32x4 mfma_bf16(short8 a, short8 b, f32x4 c) {
  return __builtin_amdgcn_mfma_f32_16x16x32_bf16(a, b, c, 0, 0, 0);
}

// ---- system-scope data plane (sc0 sc1; r6/r7-proven) ----
__device__ __forceinline__ void ld32B(const u16* b, short8* c0, short8* c1) {
  asm volatile(
    "global_load_dwordx4 %0, %2, off sc0 sc1\n\t"
    "global_load_dwordx4 %1, %2, off offset:16 sc0 sc1"
    : "=&v"(*c0), "=&v"(*c1) : "v"(b) : "memory");
}
__device__ __forceinline__ void issue2(const u16* base, short8* t) {
  asm volatile(
    "global_load_dwordx4 %0, %2, off sc0 sc1\n\t"
    "global_load_dwordx4 %1, %2, off offset:64 sc0 sc1"
    : "=&v"(t[0]), "=&v"(t[1]) : "v"(base) : "memory");
}
__device__ __forceinline__ void st16(u16* p, unsigned short v) {
  asm volatile("global_store_short %0, %1, off sc0 sc1"
               :: "v"(p), "v"((unsigned)v) : "memory");
}
__device__ __forceinline__ void stf32(float* p, float v) {
  asm volatile("global_store_dword %0, %1, off sc0 sc1" :: "v"(p), "v"(v) : "memory");
}
__device__ __forceinline__ float ldf32(const float* p) {
  float v;
  asm volatile("global_load_dword %0, %1, off sc0 sc1\n\ts_waitcnt vmcnt(0)"
               : "=&v"(v) : "v"(p) : "memory");
  __builtin_amdgcn_sched_barrier(0);
  return v;
}
__device__ __forceinline__ void waitv0() {
  asm volatile("s_waitcnt vmcnt(0)" ::: "memory");
  __builtin_amdgcn_sched_barrier(0);
}

// ---- control plane (r7 verbatim): plain sc0 sc1 epoch flags ----
__device__ __forceinline__ void wg_publish(unsigned* fa, unsigned e) {
  asm volatile("s_waitcnt vmcnt(0)" ::: "memory");
  __syncthreads();
  if (threadIdx.x == 0)
    asm volatile("global_store_dword %0, %1, off sc0 sc1" :: "v"(fa), "v"(e) : "memory");
}
__device__ __forceinline__ void pollge(const unsigned* flags, unsigned E) {
  const unsigned* addr = flags + (threadIdx.x & 15) * 8;
  int spin = 0;
  for (;;) {
    unsigned v;
    asm volatile("global_load_dword %0, %1, off sc0 sc1\n\ts_waitcnt vmcnt(0)"
                 : "=&v"(v) : "v"(addr) : "memory");
    if (__all(v >= E)) break;
    if (++spin > SPIN_MAX) break;
    __builtin_amdgcn_s_sleep(1);
  }
  __builtin_amdgcn_sched_barrier(0);
}

// ---- dtype detector ----
__global__ void detect_mode(const unsigned* __restrict__ feat, unsigned* __restrict__ flag) {
  const int t = threadIdx.x;
  int cnt = 0;
#pragma unroll
  for (int i = 0; i < 8; i++) {
    const unsigned wv = feat[t * 8 + i];
    const unsigned e = (wv >> 7) & 0xFFu;
    cnt += (e >= 100u && e <= 130u) ? 1 : 0;
  }
#pragma unroll
  for (int o = 32; o > 0; o >>= 1) cnt += __shfl_down(cnt, o, 64);
  if (t == 0) flag[0] = (cnt >= 256) ? 1u : 0u;
}

// ============================ encoder ============================
// Tick t: layer0 step t (t<672), layer1 step t-1 (t>=1). Per-wg flag after tick
// t = t+1. Tick-t reads poll >= t. Slab parity: h(t) at t&1; reads at (t+1)&1.
__global__ void __launch_bounds__(256, 1)
enc_kernel(const void* __restrict__ feat,
           const void* __restrict__ Wih0, const void* __restrict__ Whh0, const void* __restrict__ b0,
           const void* __restrict__ Wih1, const void* __restrict__ Whh1, const void* __restrict__ b1,
           char* __restrict__ ws) {
  const int mode = (int)*(const unsigned*)(ws + OFF_FLAG);
  const int tid  = threadIdx.x;
  const int lane = tid & 63;
  const int w    = tid >> 6;
  const int bId  = blockIdx.x;
  const int g    = (bId & 7) * 2 + ((bId >> 3) & 1);
  const int m    = bId >> 4;

  const int fcol = lane & 15;                // batch row
  const int kq   = lane >> 4;                // k-quarter / channel sub-index
  const int chq  = m * 16 + w * 4 + kq;      // this lane's pointwise channel
  const int bgl  = g * 16 + fcol;
  const int sr   = tid >> 4;                 // stage row (batch)
  const int sc2  = (tid & 15) * 2;           // stage col (short8 chunks)

  unsigned* fe_g = (unsigned*)(ws + OFF_FE) + g * 128;
  u16* h0s = (u16*)(ws + OFF_H0) + (size_t)g * 2 * 4096;
  u16* h1s = (u16*)(ws + OFF_H1) + (size_t)g * 2 * 4096;
  u16* f0s = (u16*)(ws + OFF_F0) + (size_t)g * 4096;
  u16* f1s = (u16*)(ws + OFF_F1) + (size_t)g * 4096;
  float* c0ws = (float*)(ws + OFF_C0);
  float* c1ws = (float*)(ws + OFF_C1);

  __shared__ short8 sh0[16][33];   // [batch][k-chunk]; 33 pads row to 528B
  __shared__ short8 sh1[16][33];

  const int n    = 16 * w + fcol;
  const int grow = (n & 3) * HDIM + m * 16 + (n >> 2);
  short8 wh0[8], wi1[8], wh1[8];
#pragma unroll
  for (int kf = 0; kf < 8; kf++) {
    const int k0 = kf * 32 + kq * 8;
    wh0[kf] = ld_frag8(Whh0, grow, HDIM, k0, mode);
    wi1[kf] = ld_frag8(Wih1, grow, HDIM, k0, mode);
    wh1[kf] = ld_frag8(Whh1, grow, HDIM, k0, mode);
  }
  float wx[4], bb0[4], bb1[4];
#pragma unroll
  for (int gt = 0; gt < 4; gt++) {
    wx[gt]  = ld_scalar(Wih0, gt * HDIM + chq, mode);
    bb0[gt] = ld_scalar(b0,   gt * HDIM + chq, mode);
    bb1[gt] = ld_scalar(b1,   gt * HDIM + chq, mode);
  }
  float c0 = 0.f, c1 = 0.f, h0keep = 0.f, h1fin = 0.f;

  for (int t = 0; t <= S_LEN; t++) {
    const int pr = (t + 1) & 1, pw = t & 1;
    short8 a0[8], a1[8];
    if (t >= 1) {
      pollge(fe_g, (unsigned)t);
      short8 va0, va1, vb0, vb1;
      ld32B(h0s + pr * 4096 + tid * 16, &va0, &va1);
      if (t >= 2) ld32B(h1s + pr * 4096 + tid * 16, &vb0, &vb1);
      waitv0();
      sh0[sr][sc2] = va0; sh0[sr][sc2 + 1] = va1;
      if (t >= 2) { sh1[sr][sc2] = vb0; sh1[sr][sc2 + 1] = vb1; }
      __syncthreads();
#pragma unroll
      for (int kf = 0; kf < 8; kf++) a0[kf] = sh0[fcol][kf * 4 + kq];
      if (t >= 2) {
#pragma unroll
        for (int kf = 0; kf < 8; kf++) a1[kf] = sh1[fcol][kf * 4 + kq];
      }
    }

    f32x4 acc0 = {0.f, 0.f, 0.f, 0.f}, acc1 = {0.f, 0.f, 0.f, 0.f};
    if (t >= 1 && t < S_LEN) {
#pragma unroll
      for (int kf = 0; kf < 8; kf++) acc0 = mfma_bf16(wh0[kf], a0[kf], acc0);  // swapped
    }
    if (t >= 1) {
#pragma unroll
      for (int kf = 0; kf < 8; kf++) acc1 = mfma_bf16(wi1[kf], a0[kf], acc1);
      if (t >= 2) {
#pragma unroll
        for (int kf = 0; kf < 8; kf++) acc1 = mfma_bf16(wh1[kf], a1[kf], acc1);
      }
    }
    // pointwise: acc[i] = gate i of (chq, batch fcol)
    if (t < S_LEN) {
      const float x = ld_scalar(feat, (long)bgl * S_LEN + t, mode);
      const float gi = acc0[0] + x * wx[0] + bb0[0];
      const float gf = acc0[1] + x * wx[1] + bb0[1];
      const float gg = acc0[2] + x * wx[2] + bb0[2];
      const float go = acc0[3] + x * wx[3] + bb0[3];
      c0 = sigm(gf) * c0 + sigm(gi) * tanhf(gg);
      const float h0v = sigm(go) * tanhf(c0);
      h0keep = h0v;
      st16(h0s + pw * 4096 + fcol * 256 + chq, f2bf(h0v));
    }
    if (t >= 1) {
      const float gi = acc1[0] + bb1[0];
      const float gf = acc1[1] + bb1[1];
      const float gg = acc1[2] + bb1[2];
      const float go = acc1[3] + bb1[3];
      c1 = sigm(gf) * c1 + sigm(gi) * tanhf(gg);
      const float h1v = sigm(go) * tanhf(c1);
      if (t < S_LEN) st16(h1s + pw * 4096 + fcol * 256 + chq, f2bf(h1v));
      else h1fin = h1v;
    }
    wg_publish(fe_g + m * 8, (unsigned)(t + 1));
  }
  // handoff (plain; kernel boundary provides ordering + writeback)
  f0s[fcol * 256 + chq] = f2bf(h0keep);
  f1s[fcol * 256 + chq] = f2bf(h1fin);
  c0ws[(size_t)bgl * HDIM + chq] = c0;
  c1ws[(size_t)bgl * HDIM + chq] = c1;
}

// ============================ decoder ============================
// Per-wg flag epochs: phase A of step s -> 3s+1, B -> 3s+2, C -> 3s+3.
// A (s>0) polls >=3s; B >=3s+1; C >=3s+2. s=0 state from fin slabs.
__global__ void __launch_bounds__(256, 1)
dec_kernel(const void* __restrict__ Wih0, const void* __restrict__ Whh0, const void* __restrict__ b0,
           const void* __restrict__ Wih1, const void* __restrict__ Whh1, const void* __restrict__ b1,
           const void* __restrict__ W1, const void* __restrict__ b1h, const void* __restrict__ W2,
           const void* __restrict__ b2, char* __restrict__ ws, void* __restrict__ out) {
  const int mode = (int)*(const unsigned*)(ws + OFF_FLAG);
  const int tid  = threadIdx.x;
  const int lane = tid & 63;
  const int w    = tid >> 6;
  const int bId  = blockIdx.x;
  const int g    = (bId & 7) * 2 + ((bId >> 3) & 1);
  const int m    = bId >> 4;

  const int fcol = lane & 15;
  const int kq   = lane >> 4;
  const int chq  = m * 16 + w * 4 + kq;
  const int bgl  = g * 16 + fcol;
  const int sr   = tid >> 4;
  const int sc2  = (tid & 15) * 2;

  unsigned* fd_g = (unsigned*)(ws + OFF_FD) + g * 128;
  u16* h0s = (u16*)(ws + OFF_H0) + (size_t)g * 2 * 4096;
  u16* h1s = (u16*)(ws + OFF_H1) + (size_t)g * 2 * 4096;
  u16* f0s = (u16*)(ws + OFF_F0) + (size_t)g * 4096;
  u16* f1s = (u16*)(ws + OFF_F1) + (size_t)g * 4096;
  float* partial = (float*)(ws + OFF_PART);
  float* c0ws = (float*)(ws + OFF_C0);
  float* c1ws = (float*)(ws + OFF_C1);

  __shared__ short8 sh0[16][33];
  __shared__ short8 sh1[16][33];
  __shared__ float part[4 * 256];
  __shared__ float redv[256];
  __shared__ float xacc[256];

  const int n    = 16 * w + fcol;
  const int grow = (n & 3) * HDIM + m * 16 + (n >> 2);
  short8 wh0[8], wi1[8], wh1[8], ww1[2];
#pragma unroll
  for (int kf = 0; kf < 8; kf++) {
    const int k0 = kf * 32 + kq * 8;
    wh0[kf] = ld_frag8(Whh0, grow, HDIM, k0, mode);
    wi1[kf] = ld_frag8(Wih1, grow, HDIM, k0, mode);
    wh1[kf] = ld_frag8(Whh1, grow, HDIM, k0, mode);
  }
#pragma unroll
  for (int kf2 = 0; kf2 < 2; kf2++) {
    const int k0 = w * 64 + kf2 * 32 + kq * 8;       // K-split of head GEMM across waves
    ww1[kf2] = ld_frag8(W1, m * 16 + fcol, HDIM, k0, mode);
  }
  float wx[4], bb0[4], bb1[4];
#pragma unroll
  for (int gt = 0; gt < 4; gt++) {
    wx[gt]  = ld_scalar(Wih0, gt * HDIM + chq, mode);
    bb0[gt] = ld_scalar(b0,   gt * HDIM + chq, mode);
    bb1[gt] = ld_scalar(b1,   gt * HDIM + chq, mode);
  }
  const int hb = tid & 15, hcl = tid >> 4;           // head reduce roles
  const float b1hv = ld_scalar(b1h, m * 16 + hcl, mode);
  const float w2v  = ld_scalar(W2,  m * 16 + hcl, mode);
  const float b2v  = ld_scalar(b2, 0, mode);

  float c0 = c0ws[(size_t)bgl * HDIM + chq];
  float c1 = c1ws[(size_t)bgl * HDIM + chq];

  for (int s = 0; s < T_LEN; s++) {
    const int ppr = (s - 1) & 1, pcur = s & 1;
    // ---------- phase A: pred(s-1) gather + layer0 ----------
    float x = 0.f;
    {
      if (s > 0) pollge(fd_g, (unsigned)(3 * s));
      short8 va0, va1;
      float pv = 0.f;
      if (s > 0) {
        ld32B(h0s + ppr * 4096 + tid * 16, &va0, &va1);
        pv = ldf32(partial + (((size_t)ppr * 16 + g) * 16 + (tid >> 4)) * 16 + (tid & 15));
      } else {
        ld32B(f0s + tid * 16, &va0, &va1);
        waitv0();
      }
      sh0[sr][sc2] = va0; sh0[sr][sc2 + 1] = va1;
      if (s > 0) xacc[(tid & 15) * 16 + (tid >> 4)] = pv;
      __syncthreads();
      if (s > 0) {
#pragma unroll
        for (int j = 0; j < 16; j++) x += xacc[fcol * 16 + j];
        if (m == 0 && tid < 16)
          st_out(out, (size_t)(g * 16 + tid) * T_LEN + (s - 1), x, mode);
      }
      short8 a0[8];
#pragma unroll
      for (int kf = 0; kf < 8; kf++) a0[kf] = sh0[fcol][kf * 4 + kq];
      f32x4 acc = {0.f, 0.f, 0.f, 0.f};
#pragma unroll
      for (int kf = 0; kf < 8; kf++) acc = mfma_bf16(wh0[kf], a0[kf], acc);
      const float gi = acc[0] + x * wx[0] + bb0[0];
      const float gf = acc[1] + x * wx[1] + bb0[1];
      const float gg = acc[2] + x * wx[2] + bb0[2];
      const float go = acc[3] + x * wx[3] + bb0[3];
      c0 = sigm(gf) * c0 + sigm(gi) * tanhf(gg);
      const float h0v = sigm(go) * tanhf(c0);
      st16(h0s + pcur * 4096 + fcol * 256 + chq, f2bf(h0v));
      wg_publish(fd_g + m * 8, (unsigned)(3 * s + 1));
    }
    // ---------- phase B: layer1 ----------
    {
      pollge(fd_g, (unsigned)(3 * s + 1));
      short8 va0, va1, vb0, vb1;
      ld32B(h0s + pcur * 4096 + tid * 16, &va0, &va1);
      ld32B(((s == 0) ? f1s : (h1s + ppr * 4096)) + tid * 16, &vb0, &vb1);
      waitv0();
      sh0[sr][sc2] = va0; sh0[sr][sc2 + 1] = va1;
      sh1[sr][sc2] = vb0; sh1[sr][sc2 + 1] = vb1;
      __syncthreads();
      short8 ay[8], a1[8];
#pragma unroll
      for (int kf = 0; kf < 8; kf++) {
        ay[kf] = sh0[fcol][kf * 4 + kq];
        a1[kf] = sh1[fcol][kf * 4 + kq];
      }
      f32x4 acc = {0.f, 0.f, 0.f, 0.f};
#pragma unroll
      for (int kf = 0; kf < 8; kf++) {
        acc = mfma_bf16(wi1[kf], ay[kf], acc);
        acc = mfma_bf16(wh1[kf], a1[kf], acc);
      }
      const float gi = acc[0] + bb1[0];
      const float gf = acc[1] + bb1[1];
      const float gg = acc[2] + bb1[2];
      const float go = acc[3] + bb1[3];
      c1 = sigm(gf) * c1 + sigm(gi) * tanhf(gg);
      const float h1v = sigm(go) * tanhf(c1);
      st16(h1s + pcur * 4096 + fcol * 256 + chq, f2bf(h1v));
      wg_publish(fd_g + m * 8, (unsigned)(3 * s + 2));
    }
    // ---------- phase C: head (Linear->ReLU->Linear), K-split across waves ----------
    {
      pollge(fd_g, (unsigned)(3 * s + 2));
      short8 ah[2];
      issue2(h1s + pcur * 4096 + fcol * 256 + w * 64 + kq * 8, ah);
      waitv0();
      f32x4 acc = {0.f, 0.f, 0.f, 0.f};
      acc = mfma_bf16(ww1[0], ah[0], acc);
      acc = mfma_bf16(ww1[1], ah[1], acc);
      // acc[i] = hidden[hch m*16 + 4kq+i][batch fcol] (K-slice w)
      *(f32x4*)&part[w * 256 + fcol * 16 + kq * 4] = acc;
      __syncthreads();
      float hid = part[0 * 256 + hb * 16 + hcl] + part[1 * 256 + hb * 16 + hcl]
                + part[2 * 256 + hb * 16 + hcl] + part[3 * 256 + hb * 16 + hcl] + b1hv;
      hid = fmaxf(hid, 0.f);
      redv[hcl * 16 + hb] = hid * w2v;
      __syncthreads();
      if (tid < 16) {
        float a = (m == 0) ? b2v : 0.f;
#pragma unroll
        for (int cc = 0; cc < 16; cc++) a += redv[cc * 16 + tid];
        stf32(partial + (((size_t)pcur * 16 + g) * 16 + m) * 16 + tid, a);
      }
      wg_publish(fd_g + m * 8, (unsigned)(3 * s + 3));
    }
  }
  // final output column: pred(T-1) from partials of step T-1 (parity 1)
  if (m == 0) {
    pollge(fd_g, (unsigned)(3 * T_LEN));
    const float pv = ldf32(partial + (((size_t)1 * 16 + g) * 16 + (tid >> 4)) * 16 + (tid & 15));
    xacc[(tid & 15) * 16 + (tid >> 4)] = pv;
    __syncthreads();
    if (tid < 16) {
      float x = 0.f;
#pragma unroll
      for (int j = 0; j < 16; j++) x += xacc[tid * 16 + j];
      st_out(out, (size_t)(g * 16 + tid) * T_LEN + (T_LEN - 1), x, mode);
    }
  }
}

extern "C" void kernel_launch(void* const* d_in, const int* in_sizes, int n_in,
                              void* d_out, int out_size, void* d_ws, size_t ws_size,
                              hipStream_t stream) {
  char* ws = (char*)d_ws;
  // zero flags + partials every launch (epoch 0 == empty; replay-safe)
  hipMemsetAsync(ws, 0, ZERO_END, stream);
  detect_mode<<<1, 64, 0, stream>>>((const unsigned*)d_in[0], (unsigned*)(ws + OFF_FLAG));
  enc_kernel<<<256, 256, 0, stream>>>(d_in[0], d_in[1], d_in[2], d_in[3],
                                      d_in[4], d_in[5], d_in[6], ws);
  dec_kernel<<<256, 256, 0, stream>>>(d_in[7], d_in[8], d_in[9], d_in[10], d_in[11], d_in[12],
                                      d_in[13], d_in[14], d_in[15], d_in[16], ws, d_out);
}